// Round 12
// baseline (32.151 us; speedup 1.0000x reference)
//
#include <hip/hip_runtime.h>

static constexpr int H = 2048;
static constexpr int W = 2048;
static constexpr int BLOCK = 1024;            // 16 waves; 1 block/CU
static constexpr int NBLOCKS = 256;           // one per CU
static constexpr int VTILES = 4096;           // r7's virtual 256-thread tile grid

__device__ __forceinline__ float fexp2(float x){ return __builtin_amdgcn_exp2f(x); }
__device__ __forceinline__ float flog2(float x){ return __builtin_amdgcn_logf(x); }
__device__ __forceinline__ float frcp (float x){ return __builtin_amdgcn_rcpf(x); }

static constexpr float LN2_ = 0.69314718055994531f;
static constexpr float S_   = 0.84932180028801905f;   // sqrt(0.5*log2(e))

// Edge exp in log2-units: t=(d*S)^2, e=exp2(-t)=exp(-d^2/2), w=e*t.
#define PAIR(e,t, u,v) float e,t; { float d_=(v)-(u); d_*=S_; const float q_=d_*d_; \
                                    e=fexp2(-q_); t=e*q_; }

// One pixel's 9-tap JS term (log2 units; final output scaled by -ln2):
//   G = 1+sum e ; St = sum e*t ; pacc = St_p/Gp + St_q/Gq + log2(Gp*Gq)
//        + 2*sum m*log2 m,   m = 0.5*(eA/Gp + eB/Gq)
__device__ __forceinline__ float pixel_term(
    float an0, float an1, float an2, float ca,
    float hAe0, float hAw0, float hAe1, float hAw1,
    float vAe0, float vAw0, float vAe1, float vAw1, float vAe2, float vAw2,
    float bn0, float bn1, float bn2, float cb,
    float hBe0, float hBw0, float hBe1, float hBw1,
    float vBe0, float vBw0, float vBe1, float vBw1, float vBe2, float vBw2)
{
    PAIR(iAe0, iAw0, an0, ca)  PAIR(iAe1, iAw1, an1, ca)  PAIR(iAe2, iAw2, an2, ca)
    PAIR(iBe0, iBw0, bn0, cb)  PAIR(iBe1, iBw1, bn1, cb)  PAIR(iBe2, iBw2, bn2, cb)

    const float Gp  = 1.f + hAe0 + hAe1 + vAe0 + vAe1 + vAe2 + iAe0 + iAe1 + iAe2;
    const float Spw =       hAw0 + hAw1 + vAw0 + vAw1 + vAw2 + iAw0 + iAw1 + iAw2;
    const float Gq  = 1.f + hBe0 + hBe1 + vBe0 + vBe1 + vBe2 + iBe0 + iBe1 + iBe2;
    const float Sqw =       hBw0 + hBw1 + vBw0 + vBw1 + vBw2 + iBw0 + iBw1 + iBw2;

    const float P  = Gp * Gq;
    const float rP = frcp(P);                 // one rcp serves both images
    const float ip = rP * Gq;
    const float iq = rP * Gp;
    const float hp = 0.5f * ip, hq = 0.5f * iq;

    float m = hp + hq;                        // center tap (e=1 both)
    float mll = m * flog2(m);
#define MT(ea, eb) m = fmaf((ea), hp, (eb)*hq); mll = fmaf(m, flog2(m), mll);
    MT(hAe0, hBe0) MT(hAe1, hBe1)
    MT(vAe0, vBe0) MT(vAe1, vBe1) MT(vAe2, vBe2)
    MT(iAe0, iBe0) MT(iAe1, iBe1) MT(iAe2, iBe2)
#undef MT

    return fmaf(ip, Spw, iq * Sqw) + flog2(P) + 2.f * mll;
}

__global__ __launch_bounds__(BLOCK, 4) void jsd_kernel(
    const float* __restrict__ A, const float* __restrict__ B,
    float* __restrict__ out)
{
    const int sub  = threadIdx.x >> 8;         // 0..3: virtual 256-thread block
    const int stid = threadIdx.x & 255;

    float total = 0.f;

    #pragma unroll 1
    for (int k = 0; k < 4; ++k) {
        const int vb = (blockIdx.x * 4 + sub) * 4 + k;   // 0..VTILES-1
        const int y0 = (vb >> 2) << 1;                   // top pixel row (R1)
        const int x0 = ((vb & 3) << 9) + (stid << 1);
        const int base = y0 * W + x0;
        const bool hasL = (x0 > 0);
        const bool hasR = (x0 + 2 < W);

        // Rows R0=y0-1(masked), R1=y0, R2=y0+1, R3=y0+2(masked); cols x0-1..x0+2
        float a00,a01,a02,a03, a10,a11,a12,a13, a20,a21,a22,a23, a30,a31,a32,a33;
        float b00,b01,b02,b03, b10,b11,b12,b13, b20,b21,b22,b23, b30,b31,b32,b33;

#define LOAD_ROW(p0,p1,p2,p3, ptr, off) \
        { const float2 q_ = *(const float2*)((ptr)+(off)); p1=q_.x; p2=q_.y; \
          p0 = hasL ? (ptr)[(off)-1] : 0.f; p3 = hasR ? (ptr)[(off)+2] : 0.f; }

        LOAD_ROW(a10,a11,a12,a13, A, base)
        LOAD_ROW(a20,a21,a22,a23, A, base + W)
        LOAD_ROW(b10,b11,b12,b13, B, base)
        LOAD_ROW(b20,b21,b22,b23, B, base + W)
        if (y0 > 0) {                                     // sub-uniform branch
            LOAD_ROW(a00,a01,a02,a03, A, base - W)
            LOAD_ROW(b00,b01,b02,b03, B, base - W)
        } else { a00=a01=a02=a03=0.f; b00=b01=b02=b03=0.f; }
        if (y0 + 2 < H) {
            LOAD_ROW(a30,a31,a32,a33, A, base + 2*W)
            LOAD_ROW(b30,b31,b32,b33, B, base + 2*W)
        } else { a30=a31=a32=a33=0.f; b30=b31=b32=b33=0.f; }
#undef LOAD_ROW

        // Shared edges (each used by 2 pixels): horizontal in R1,R2; R1<->R2.
        PAIR(hA10,tA10, a10,a11) PAIR(hA11,tA11, a11,a12) PAIR(hA12,tA12, a12,a13)
        PAIR(hA20,tA20, a20,a21) PAIR(hA21,tA21, a21,a22) PAIR(hA22,tA22, a22,a23)
        PAIR(hB10,tB10, b10,b11) PAIR(hB11,tB11, b11,b12) PAIR(hB12,tB12, b12,b13)
        PAIR(hB20,tB20, b20,b21) PAIR(hB21,tB21, b21,b22) PAIR(hB22,tB22, b22,b23)
        PAIR(vA10,wA10, a11,a20) PAIR(vA11,wA11, a11,a21) PAIR(vA12,wA12, a11,a22)
        PAIR(vA21,wA21, a12,a21) PAIR(vA22,wA22, a12,a22) PAIR(vA23,wA23, a12,a23)
        PAIR(vA01,wA01, a10,a21) PAIR(vA32,wA32, a13,a22)
        PAIR(vB10,wB10, b11,b20) PAIR(vB11,wB11, b11,b21) PAIR(vB12,wB12, b11,b22)
        PAIR(vB21,wB21, b12,b21) PAIR(vB22,wB22, b12,b22) PAIR(vB23,wB23, b12,b23)
        PAIR(vB01,wB01, b10,b21) PAIR(vB32,wB32, b13,b22)

        // (R1,C1): up = R0 cols 0..2; down edges v10,v11,v12
        total += pixel_term(a00,a01,a02, a11, hA10,tA10, hA11,tA11,
                            vA10,wA10, vA11,wA11, vA12,wA12,
                            b00,b01,b02, b11, hB10,tB10, hB11,tB11,
                            vB10,wB10, vB11,wB11, vB12,wB12);
        // (R1,C2): up = R0 cols 1..3; down edges v21,v22,v23
        total += pixel_term(a01,a02,a03, a12, hA11,tA11, hA12,tA12,
                            vA21,wA21, vA22,wA22, vA23,wA23,
                            b01,b02,b03, b12, hB11,tB11, hB12,tB12,
                            vB21,wB21, vB22,wB22, vB23,wB23);
        // (R2,C1): down = R3 cols 0..2; up edges v01,v11,v21
        total += pixel_term(a30,a31,a32, a21, hA20,tA20, hA21,tA21,
                            vA01,wA01, vA11,wA11, vA21,wA21,
                            b30,b31,b32, b21, hB20,tB20, hB21,tB21,
                            vB01,wB01, vB11,wB11, vB21,wB21);
        // (R2,C2): down = R3 cols 1..3; up edges v12,v22,v32
        total += pixel_term(a31,a32,a33, a22, hA21,tA21, hA22,tA22,
                            vA12,wA12, vA22,wA22, vA32,wA32,
                            b31,b32,b33, b22, hB21,tB21, hB22,tB22,
                            vB12,wB12, vB22,wB22, vB32,wB32);
    }

    // wave64 reduce, cross-wave via LDS, one atomic per block (256 total).
    #pragma unroll
    for (int off = 32; off > 0; off >>= 1)
        total += __shfl_down(total, off, 64);

    __shared__ float wsum[BLOCK / 64];
    const int lane = threadIdx.x & 63;
    const int wid  = threadIdx.x >> 6;
    if (lane == 0) wsum[wid] = total;
    __syncthreads();
    if (threadIdx.x == 0) {
        float s = 0.f;
        #pragma unroll
        for (int i = 0; i < BLOCK / 64; ++i) s += wsum[i];
        atomicAdd(out, -LN2_ * s);
    }
}

extern "C" void kernel_launch(void* const* d_in, const int* in_sizes, int n_in,
                              void* d_out, int out_size, void* d_ws, size_t ws_size,
                              hipStream_t stream) {
    const float* A = (const float*)d_in[0];
    const float* B = (const float*)d_in[1];
    float* out = (float*)d_out;

    (void)hipMemsetAsync(out, 0, sizeof(float), stream);   // accumulator base
    jsd_kernel<<<NBLOCKS, BLOCK, 0, stream>>>(A, B, out);
}

// Round 13
// 27.174 us; speedup vs baseline: 1.1832x; 1.1832x over previous
//
#include <hip/hip_runtime.h>

static constexpr int H = 2048;
static constexpr int W = 2048;
static constexpr int BLOCK = 256;
// 2 cols x 2 rows of pixels per thread; block tile = 512 cols x 2 rows
static constexpr int NBLOCKS = (H / 2) * (W / (BLOCK * 2));   // 4096
static constexpr int RBLOCK = 1024;

__device__ __forceinline__ float fexp2(float x){ return __builtin_amdgcn_exp2f(x); }
__device__ __forceinline__ float flog2(float x){ return __builtin_amdgcn_logf(x); }
__device__ __forceinline__ float frcp (float x){ return __builtin_amdgcn_rcpf(x); }

static constexpr float LN2_ = 0.69314718055994531f;
static constexpr float S_   = 0.84932180028801905f;   // sqrt(0.5*log2(e))

// Edge exp in log2-units: t=(d*S)^2, e=exp2(-t)=exp(-d^2/2), w=e*t.
#define PAIR(e,t, u,v) float e,t; { float d_=(v)-(u); d_*=S_; const float q_=d_*d_; \
                                    e=fexp2(-q_); t=e*q_; }

// One pixel's 9-tap JS term (log2 units; final output scaled by -ln2).
// All reductions pairwise-tree'd for ILP (FP order fixed but shallow).
__device__ __forceinline__ float pixel_term(
    float an0, float an1, float an2, float ca,
    float hAe0, float hAw0, float hAe1, float hAw1,
    float vAe0, float vAw0, float vAe1, float vAw1, float vAe2, float vAw2,
    float bn0, float bn1, float bn2, float cb,
    float hBe0, float hBw0, float hBe1, float hBw1,
    float vBe0, float vBw0, float vBe1, float vBw1, float vBe2, float vBw2)
{
    PAIR(iAe0, iAw0, an0, ca)  PAIR(iAe1, iAw1, an1, ca)  PAIR(iAe2, iAw2, an2, ca)
    PAIR(iBe0, iBw0, bn0, cb)  PAIR(iBe1, iBw1, bn1, cb)  PAIR(iBe2, iBw2, bn2, cb)

    // pairwise trees (depth 3-4 instead of serial depth 8)
    const float Gp  = ((1.f + hAe0) + (hAe1 + vAe0)) + ((vAe1 + vAe2) + (iAe0 + (iAe1 + iAe2)));
    const float Spw = ((hAw0 + hAw1) + (vAw0 + vAw1)) + ((vAw2 + iAw0) + (iAw1 + iAw2));
    const float Gq  = ((1.f + hBe0) + (hBe1 + vBe0)) + ((vBe1 + vBe2) + (iBe0 + (iBe1 + iBe2)));
    const float Sqw = ((hBw0 + hBw1) + (vBw0 + vBw1)) + ((vBw2 + iBw0) + (iBw1 + iBw2));

    const float P  = Gp * Gq;
    const float rP = frcp(P);                 // one rcp serves both images
    const float ip = rP * Gq;
    const float iq = rP * Gp;
    const float hp = 0.5f * ip, hq = 0.5f * iq;

    // two independent m*log2(m) chains (depth ~5 each instead of 9)
    float m0 = hp + hq;                       // center tap (e=1 both)
    float mllA = m0 * flog2(m0);
    float m1 = fmaf(hAe0, hp, hBe0 * hq);
    float mllB = m1 * flog2(m1);
#define MTA(ea, eb) { const float m_ = fmaf((ea), hp, (eb)*hq); \
                      mllA = fmaf(m_, flog2(m_), mllA); }
#define MTB(ea, eb) { const float m_ = fmaf((ea), hp, (eb)*hq); \
                      mllB = fmaf(m_, flog2(m_), mllB); }
    MTA(hAe1, hBe1)
    MTB(vAe0, vBe0)  MTA(vAe1, vBe1)  MTB(vAe2, vBe2)
    MTA(iAe0, iBe0)  MTB(iAe1, iBe1)  MTA(iAe2, iBe2)
#undef MTA
#undef MTB

    return (fmaf(ip, Spw, iq * Sqw) + flog2(P)) + 2.f * (mllA + mllB);
}

__global__ __launch_bounds__(BLOCK, 4) void jsd_pixel_kernel(
    const float* __restrict__ A, const float* __restrict__ B,
    float* __restrict__ partial)
{
    const int bid   = blockIdx.x;
    const int ytile = bid >> 2;                      // 1024 row-pairs
    const int y0    = ytile << 1;                    // top pixel row (R1)
    const int x0    = ((bid & 3) << 9) + (threadIdx.x << 1);
    const int base  = y0 * W + x0;
    const bool hasL = (x0 > 0);
    const bool hasR = (x0 + 2 < W);

    // Rows: R0=y0-1 (masked), R1=y0, R2=y0+1, R3=y0+2 (masked). Cols x0-1..x0+2.
    float a00,a01,a02,a03, a10,a11,a12,a13, a20,a21,a22,a23, a30,a31,a32,a33;
    float b00,b01,b02,b03, b10,b11,b12,b13, b20,b21,b22,b23, b30,b31,b32,b33;

#define LOAD_ROW(p0,p1,p2,p3, ptr, off) \
    { const float2 q_ = *(const float2*)((ptr)+(off)); p1=q_.x; p2=q_.y; \
      p0 = hasL ? (ptr)[(off)-1] : 0.f; p3 = hasR ? (ptr)[(off)+2] : 0.f; }

    LOAD_ROW(a10,a11,a12,a13, A, base)
    LOAD_ROW(a20,a21,a22,a23, A, base + W)
    LOAD_ROW(b10,b11,b12,b13, B, base)
    LOAD_ROW(b20,b21,b22,b23, B, base + W)
    if (y0 > 0) {                                     // block-uniform
        LOAD_ROW(a00,a01,a02,a03, A, base - W)
        LOAD_ROW(b00,b01,b02,b03, B, base - W)
    } else { a00=a01=a02=a03=0.f; b00=b01=b02=b03=0.f; }
    if (y0 + 2 < H) {
        LOAD_ROW(a30,a31,a32,a33, A, base + 2*W)
        LOAD_ROW(b30,b31,b32,b33, B, base + 2*W)
    } else { a30=a31=a32=a33=0.f; b30=b31=b32=b33=0.f; }
#undef LOAD_ROW

    // Shared-edge exps. Horizontal pairs in rows R1,R2; all R1<->R2 edges.
    PAIR(hA10,tA10, a10,a11) PAIR(hA11,tA11, a11,a12) PAIR(hA12,tA12, a12,a13)
    PAIR(hA20,tA20, a20,a21) PAIR(hA21,tA21, a21,a22) PAIR(hA22,tA22, a22,a23)
    PAIR(hB10,tB10, b10,b11) PAIR(hB11,tB11, b11,b12) PAIR(hB12,tB12, b12,b13)
    PAIR(hB20,tB20, b20,b21) PAIR(hB21,tB21, b21,b22) PAIR(hB22,tB22, b22,b23)
    PAIR(vA10,wA10, a11,a20) PAIR(vA11,wA11, a11,a21) PAIR(vA12,wA12, a11,a22)
    PAIR(vA21,wA21, a12,a21) PAIR(vA22,wA22, a12,a22) PAIR(vA23,wA23, a12,a23)
    PAIR(vA01,wA01, a10,a21) PAIR(vA32,wA32, a13,a22)
    PAIR(vB10,wB10, b11,b20) PAIR(vB11,wB11, b11,b21) PAIR(vB12,wB12, b11,b22)
    PAIR(vB21,wB21, b12,b21) PAIR(vB22,wB22, b12,b22) PAIR(vB23,wB23, b12,b23)
    PAIR(vB01,wB01, b10,b21) PAIR(vB32,wB32, b13,b22)

    // (R1,C1): up = R0 cols 0..2; down edges v10,v11,v12
    const float t0 = pixel_term(a00,a01,a02, a11, hA10,tA10, hA11,tA11,
                                vA10,wA10, vA11,wA11, vA12,wA12,
                                b00,b01,b02, b11, hB10,tB10, hB11,tB11,
                                vB10,wB10, vB11,wB11, vB12,wB12);
    // (R1,C2): up = R0 cols 1..3; down edges v21,v22,v23
    const float t1 = pixel_term(a01,a02,a03, a12, hA11,tA11, hA12,tA12,
                                vA21,wA21, vA22,wA22, vA23,wA23,
                                b01,b02,b03, b12, hB11,tB11, hB12,tB12,
                                vB21,wB21, vB22,wB22, vB23,wB23);
    // (R2,C1): down = R3 cols 0..2; up edges v01,v11,v21
    const float t2 = pixel_term(a30,a31,a32, a21, hA20,tA20, hA21,tA21,
                                vA01,wA01, vA11,wA11, vA21,wA21,
                                b30,b31,b32, b21, hB20,tB20, hB21,tB21,
                                vB01,wB01, vB11,wB11, vB21,wB21);
    // (R2,C2): down = R3 cols 1..3; up edges v12,v22,v32
    const float t3 = pixel_term(a31,a32,a33, a22, hA21,tA21, hA22,tA22,
                                vA12,wA12, vA22,wA22, vA32,wA32,
                                b31,b32,b33, b22, hB21,tB21, hB22,tB22,
                                vB12,wB12, vB22,wB22, vB32,wB32);
    float pacc = (t0 + t1) + (t2 + t3);

    // wave64 reduce, cross-wave via LDS
    #pragma unroll
    for (int off = 32; off > 0; off >>= 1)
        pacc += __shfl_down(pacc, off, 64);

    __shared__ float wsum[BLOCK / 64];
    const int lane = threadIdx.x & 63;
    const int wid  = threadIdx.x >> 6;
    if (lane == 0) wsum[wid] = pacc;
    __syncthreads();
    if (threadIdx.x == 0)
        partial[blockIdx.x] = (wsum[0] + wsum[1]) + (wsum[2] + wsum[3]);
}

// Deterministic final reduce of NBLOCKS partials (single block, 16 waves).
__global__ __launch_bounds__(RBLOCK) void jsd_final_reduce(
    const float* __restrict__ partial, float* __restrict__ out)
{
    float s = 0.f;
    #pragma unroll
    for (int i = 0; i < NBLOCKS / RBLOCK; ++i)
        s += partial[i * RBLOCK + threadIdx.x];

    #pragma unroll
    for (int off = 32; off > 0; off >>= 1)
        s += __shfl_down(s, off, 64);

    __shared__ float wsum[RBLOCK / 64];
    const int lane = threadIdx.x & 63;
    const int wid  = threadIdx.x >> 6;
    if (lane == 0) wsum[wid] = s;
    __syncthreads();
    if (threadIdx.x == 0) {
        float t = 0.f;
        #pragma unroll
        for (int i = 0; i < RBLOCK / 64; ++i) t += wsum[i];
        out[0] = -LN2_ * t;
    }
}

extern "C" void kernel_launch(void* const* d_in, const int* in_sizes, int n_in,
                              void* d_out, int out_size, void* d_ws, size_t ws_size,
                              hipStream_t stream) {
    const float* A = (const float*)d_in[0];
    const float* B = (const float*)d_in[1];
    float* out = (float*)d_out;
    float* partial = (float*)d_ws;    // NBLOCKS floats = 16 KiB

    jsd_pixel_kernel<<<NBLOCKS, BLOCK, 0, stream>>>(A, B, partial);
    jsd_final_reduce<<<1, RBLOCK, 0, stream>>>(partial, out);
}

// Round 14
// 27.063 us; speedup vs baseline: 1.1880x; 1.0041x over previous
//
#include <hip/hip_runtime.h>

static constexpr int H = 2048;
static constexpr int W = 2048;
static constexpr int BLOCK = 256;
// 4 cols x 2 rows of pixels per thread; block tile = 1024 cols x 2 rows
static constexpr int NBLOCKS = (H / 2) * (W / (BLOCK * 4));   // 1024*2 = 2048
static constexpr int RBLOCK = 1024;

__device__ __forceinline__ float fexp2(float x){ return __builtin_amdgcn_exp2f(x); }
__device__ __forceinline__ float flog2(float x){ return __builtin_amdgcn_logf(x); }
__device__ __forceinline__ float frcp (float x){ return __builtin_amdgcn_rcpf(x); }

static constexpr float LN2_ = 0.69314718055994531f;
static constexpr float S_   = 0.84932180028801905f;   // sqrt(0.5*log2(e))

// Edge exp in log2-units: t=(d*S)^2, e=exp2(-t)=exp(-d^2/2), w=e*t.
#define PAIR(e,t, u,v) float e,t; { float d_=(v)-(u); d_*=S_; const float q_=d_*d_; \
                                    e=fexp2(-q_); t=e*q_; }

// One pixel's 9-tap JS term from its 8 precomputed (e,w) edge pairs per image.
// (log2 units; final output scaled by -ln2 in the reduce kernel)
__device__ __forceinline__ float pixel_term8(
    float a0,float u0, float a1,float u1, float a2,float u2, float a3,float u3,
    float a4,float u4, float a5,float u5, float a6,float u6, float a7,float u7,
    float b0,float v0, float b1,float v1, float b2,float v2, float b3,float v3,
    float b4,float v4, float b5,float v5, float b6,float v6, float b7,float v7)
{
    const float Gp  = ((1.f + a0) + (a1 + a2)) + ((a3 + a4) + (a5 + (a6 + a7)));
    const float Spw = ((u0 + u1) + (u2 + u3)) + ((u4 + u5) + (u6 + u7));
    const float Gq  = ((1.f + b0) + (b1 + b2)) + ((b3 + b4) + (b5 + (b6 + b7)));
    const float Sqw = ((v0 + v1) + (v2 + v3)) + ((v4 + v5) + (v6 + v7));

    const float P  = Gp * Gq;
    const float rP = frcp(P);                 // one rcp serves both images
    const float ip = rP * Gq;
    const float iq = rP * Gp;
    const float hp = 0.5f * ip, hq = 0.5f * iq;

    float m0 = hp + hq;                       // center tap (e=1 both)
    float mllA = m0 * flog2(m0);
    float m1 = fmaf(a0, hp, b0 * hq);
    float mllB = m1 * flog2(m1);
#define MTA(ea, eb) { const float m_ = fmaf((ea), hp, (eb)*hq); \
                      mllA = fmaf(m_, flog2(m_), mllA); }
#define MTB(ea, eb) { const float m_ = fmaf((ea), hp, (eb)*hq); \
                      mllB = fmaf(m_, flog2(m_), mllB); }
    MTA(a1,b1) MTB(a2,b2) MTA(a3,b3) MTB(a4,b4) MTA(a5,b5) MTB(a6,b6) MTA(a7,b7)
#undef MTA
#undef MTB

    return (fmaf(ip, Spw, iq * Sqw) + flog2(P)) + 2.f * (mllA + mllB);
}

__global__ __launch_bounds__(BLOCK, 3) void jsd_pixel_kernel(
    const float* __restrict__ A, const float* __restrict__ B,
    float* __restrict__ partial)
{
    const int bid  = blockIdx.x;
    const int y0   = (bid >> 1) << 1;                // top pixel row (R1)
    const int col0 = ((bid & 1) << 10) + (threadIdx.x << 2);
    const int base = y0 * W + col0;
    const bool hasL = (col0 > 0);
    const bool hasR = (col0 + 4 < W);

    // Inputs: rows R0=y0-1(masked), R1=y0, R2=y0+1, R3=y0+2(masked);
    // cols 0..5 = col0-1 .. col0+4 (pixels at cols 1..4).
    float a00,a01,a02,a03,a04,a05, a10,a11,a12,a13,a14,a15;
    float a20,a21,a22,a23,a24,a25, a30,a31,a32,a33,a34,a35;
    float b00,b01,b02,b03,b04,b05, b10,b11,b12,b13,b14,b15;
    float b20,b21,b22,b23,b24,b25, b30,b31,b32,b33,b34,b35;

#define LOAD_ROW6(p0,p1,p2,p3,p4,p5, ptr, off) \
    { const float4 q_ = *(const float4*)((ptr)+(off)); \
      p1=q_.x; p2=q_.y; p3=q_.z; p4=q_.w; \
      p0 = hasL ? (ptr)[(off)-1] : 0.f; p5 = hasR ? (ptr)[(off)+4] : 0.f; }

    LOAD_ROW6(a10,a11,a12,a13,a14,a15, A, base)
    LOAD_ROW6(a20,a21,a22,a23,a24,a25, A, base + W)
    LOAD_ROW6(b10,b11,b12,b13,b14,b15, B, base)
    LOAD_ROW6(b20,b21,b22,b23,b24,b25, B, base + W)
    if (y0 > 0) {                                     // block-uniform
        LOAD_ROW6(a00,a01,a02,a03,a04,a05, A, base - W)
        LOAD_ROW6(b00,b01,b02,b03,b04,b05, B, base - W)
    } else { a00=a01=a02=a03=a04=a05=0.f; b00=b01=b02=b03=b04=b05=0.f; }
    if (y0 + 2 < H) {
        LOAD_ROW6(a30,a31,a32,a33,a34,a35, A, base + 2*W)
        LOAD_ROW6(b30,b31,b32,b33,b34,b35, B, base + 2*W)
    } else { a30=a31=a32=a33=a34=a35=0.f; b30=b31=b32=b33=b34=b35=0.f; }
#undef LOAD_ROW6

    // 16 shared edges per image (each consumed by exactly 2 pixels).
    // H row R1 / R2 between pixel cols; V same-col; p = down-right; q = down-left.
    PAIR(hA1a,sA1a, a11,a12) PAIR(hA1b,sA1b, a12,a13) PAIR(hA1c,sA1c, a13,a14)
    PAIR(hA2a,sA2a, a21,a22) PAIR(hA2b,sA2b, a22,a23) PAIR(hA2c,sA2c, a23,a24)
    PAIR(vA1,xA1, a11,a21) PAIR(vA2,xA2, a12,a22) PAIR(vA3,xA3, a13,a23) PAIR(vA4,xA4, a14,a24)
    PAIR(pA1,yA1, a11,a22) PAIR(pA2,yA2, a12,a23) PAIR(pA3,yA3, a13,a24)
    PAIR(qA1,zA1, a12,a21) PAIR(qA2,zA2, a13,a22) PAIR(qA3,zA3, a14,a23)
    PAIR(hB1a,sB1a, b11,b12) PAIR(hB1b,sB1b, b12,b13) PAIR(hB1c,sB1c, b13,b14)
    PAIR(hB2a,sB2a, b21,b22) PAIR(hB2b,sB2b, b22,b23) PAIR(hB2c,sB2c, b23,b24)
    PAIR(vB1,xB1, b11,b21) PAIR(vB2,xB2, b12,b22) PAIR(vB3,xB3, b13,b23) PAIR(vB4,xB4, b14,b24)
    PAIR(pB1,yB1, b11,b22) PAIR(pB2,yB2, b12,b23) PAIR(pB3,yB3, b13,b24)
    PAIR(qB1,zB1, b12,b21) PAIR(qB2,zB2, b13,b22) PAIR(qB3,zB3, b14,b23)

    float pacc = 0.f;

    { // P11 (R1,c1): unshared up3 + H-left + diag-LD; shared h1a, v1, p1
      PAIR(ua0,wa0, a00,a11) PAIR(ua1,wa1, a01,a11) PAIR(ua2,wa2, a02,a11)
      PAIR(ua3,wa3, a10,a11) PAIR(ua4,wa4, a11,a20)
      PAIR(ub0,wb0, b00,b11) PAIR(ub1,wb1, b01,b11) PAIR(ub2,wb2, b02,b11)
      PAIR(ub3,wb3, b10,b11) PAIR(ub4,wb4, b11,b20)
      pacc += pixel_term8(ua0,wa0, ua1,wa1, ua2,wa2, ua3,wa3, ua4,wa4,
                          hA1a,sA1a, vA1,xA1, pA1,yA1,
                          ub0,wb0, ub1,wb1, ub2,wb2, ub3,wb3, ub4,wb4,
                          hB1a,sB1a, vB1,xB1, pB1,yB1);
    }
    { // P12 (R1,c2): unshared up3; shared h1a, h1b, q1, v2, p2
      PAIR(ua0,wa0, a01,a12) PAIR(ua1,wa1, a02,a12) PAIR(ua2,wa2, a03,a12)
      PAIR(ub0,wb0, b01,b12) PAIR(ub1,wb1, b02,b12) PAIR(ub2,wb2, b03,b12)
      pacc += pixel_term8(ua0,wa0, ua1,wa1, ua2,wa2, hA1a,sA1a, hA1b,sA1b,
                          qA1,zA1, vA2,xA2, pA2,yA2,
                          ub0,wb0, ub1,wb1, ub2,wb2, hB1a,sB1a, hB1b,sB1b,
                          qB1,zB1, vB2,xB2, pB2,yB2);
    }
    { // P13 (R1,c3): unshared up3; shared h1b, h1c, q2, v3, p3
      PAIR(ua0,wa0, a02,a13) PAIR(ua1,wa1, a03,a13) PAIR(ua2,wa2, a04,a13)
      PAIR(ub0,wb0, b02,b13) PAIR(ub1,wb1, b03,b13) PAIR(ub2,wb2, b04,b13)
      pacc += pixel_term8(ua0,wa0, ua1,wa1, ua2,wa2, hA1b,sA1b, hA1c,sA1c,
                          qA2,zA2, vA3,xA3, pA3,yA3,
                          ub0,wb0, ub1,wb1, ub2,wb2, hB1b,sB1b, hB1c,sB1c,
                          qB2,zB2, vB3,xB3, pB3,yB3);
    }
    { // P14 (R1,c4): unshared up3 + H-right + diag-RD; shared h1c, q3, v4
      PAIR(ua0,wa0, a03,a14) PAIR(ua1,wa1, a04,a14) PAIR(ua2,wa2, a05,a14)
      PAIR(ua3,wa3, a14,a15) PAIR(ua4,wa4, a14,a25)
      PAIR(ub0,wb0, b03,b14) PAIR(ub1,wb1, b04,b14) PAIR(ub2,wb2, b05,b14)
      PAIR(ub3,wb3, b14,b15) PAIR(ub4,wb4, b14,b25)
      pacc += pixel_term8(ua0,wa0, ua1,wa1, ua2,wa2, ua3,wa3, ua4,wa4,
                          hA1c,sA1c, qA3,zA3, vA4,xA4,
                          ub0,wb0, ub1,wb1, ub2,wb2, ub3,wb3, ub4,wb4,
                          hB1c,sB1c, qB3,zB3, vB4,xB4);
    }
    { // P21 (R2,c1): unshared down3 + H-left + diag-LU; shared h2a, v1, q1
      PAIR(ua0,wa0, a30,a21) PAIR(ua1,wa1, a31,a21) PAIR(ua2,wa2, a32,a21)
      PAIR(ua3,wa3, a20,a21) PAIR(ua4,wa4, a10,a21)
      PAIR(ub0,wb0, b30,b21) PAIR(ub1,wb1, b31,b21) PAIR(ub2,wb2, b32,b21)
      PAIR(ub3,wb3, b20,b21) PAIR(ub4,wb4, b10,b21)
      pacc += pixel_term8(ua0,wa0, ua1,wa1, ua2,wa2, ua3,wa3, ua4,wa4,
                          hA2a,sA2a, vA1,xA1, qA1,zA1,
                          ub0,wb0, ub1,wb1, ub2,wb2, ub3,wb3, ub4,wb4,
                          hB2a,sB2a, vB1,xB1, qB1,zB1);
    }
    { // P22 (R2,c2): unshared down3; shared h2a, h2b, p1, v2, q2
      PAIR(ua0,wa0, a31,a22) PAIR(ua1,wa1, a32,a22) PAIR(ua2,wa2, a33,a22)
      PAIR(ub0,wb0, b31,b22) PAIR(ub1,wb1, b32,b22) PAIR(ub2,wb2, b33,b22)
      pacc += pixel_term8(ua0,wa0, ua1,wa1, ua2,wa2, hA2a,sA2a, hA2b,sA2b,
                          pA1,yA1, vA2,xA2, qA2,zA2,
                          ub0,wb0, ub1,wb1, ub2,wb2, hB2a,sB2a, hB2b,sB2b,
                          pB1,yB1, vB2,xB2, qB2,zB2);
    }
    { // P23 (R2,c3): unshared down3; shared h2b, h2c, p2, v3, q3
      PAIR(ua0,wa0, a32,a23) PAIR(ua1,wa1, a33,a23) PAIR(ua2,wa2, a34,a23)
      PAIR(ub0,wb0, b32,b23) PAIR(ub1,wb1, b33,b23) PAIR(ub2,wb2, b34,b23)
      pacc += pixel_term8(ua0,wa0, ua1,wa1, ua2,wa2, hA2b,sA2b, hA2c,sA2c,
                          pA2,yA2, vA3,xA3, qA3,zA3,
                          ub0,wb0, ub1,wb1, ub2,wb2, hB2b,sB2b, hB2c,sB2c,
                          pB2,yB2, vB3,xB3, qB3,zB3);
    }
    { // P24 (R2,c4): unshared down3 + H-right + diag-RU; shared h2c, p3, v4
      PAIR(ua0,wa0, a33,a24) PAIR(ua1,wa1, a34,a24) PAIR(ua2,wa2, a35,a24)
      PAIR(ua3,wa3, a24,a25) PAIR(ua4,wa4, a15,a24)
      PAIR(ub0,wb0, b33,b24) PAIR(ub1,wb1, b34,b24) PAIR(ub2,wb2, b35,b24)
      PAIR(ub3,wb3, b24,b25) PAIR(ub4,wb4, b15,b24)
      pacc += pixel_term8(ua0,wa0, ua1,wa1, ua2,wa2, ua3,wa3, ua4,wa4,
                          hA2c,sA2c, pA3,yA3, vA4,xA4,
                          ub0,wb0, ub1,wb1, ub2,wb2, ub3,wb3, ub4,wb4,
                          hB2c,sB2c, pB3,yB3, vB4,xB4);
    }

    // wave64 reduce, cross-wave via LDS
    #pragma unroll
    for (int off = 32; off > 0; off >>= 1)
        pacc += __shfl_down(pacc, off, 64);

    __shared__ float wsum[BLOCK / 64];
    const int lane = threadIdx.x & 63;
    const int wid  = threadIdx.x >> 6;
    if (lane == 0) wsum[wid] = pacc;
    __syncthreads();
    if (threadIdx.x == 0)
        partial[blockIdx.x] = (wsum[0] + wsum[1]) + (wsum[2] + wsum[3]);
}

// Deterministic final reduce of NBLOCKS partials (single block, 16 waves).
__global__ __launch_bounds__(RBLOCK) void jsd_final_reduce(
    const float* __restrict__ partial, float* __restrict__ out)
{
    float s = 0.f;
    #pragma unroll
    for (int i = 0; i < NBLOCKS / RBLOCK; ++i)
        s += partial[i * RBLOCK + threadIdx.x];

    #pragma unroll
    for (int off = 32; off > 0; off >>= 1)
        s += __shfl_down(s, off, 64);

    __shared__ float wsum[RBLOCK / 64];
    const int lane = threadIdx.x & 63;
    const int wid  = threadIdx.x >> 6;
    if (lane == 0) wsum[wid] = s;
    __syncthreads();
    if (threadIdx.x == 0) {
        float t = 0.f;
        #pragma unroll
        for (int i = 0; i < RBLOCK / 64; ++i) t += wsum[i];
        out[0] = -LN2_ * t;
    }
}

extern "C" void kernel_launch(void* const* d_in, const int* in_sizes, int n_in,
                              void* d_out, int out_size, void* d_ws, size_t ws_size,
                              hipStream_t stream) {
    const float* A = (const float*)d_in[0];
    const float* B = (const float*)d_in[1];
    float* out = (float*)d_out;
    float* partial = (float*)d_ws;    // NBLOCKS floats = 8 KiB

    jsd_pixel_kernel<<<NBLOCKS, BLOCK, 0, stream>>>(A, B, partial);
    jsd_final_reduce<<<1, RBLOCK, 0, stream>>>(partial, out);
}

// Round 15
// 26.805 us; speedup vs baseline: 1.1994x; 1.0096x over previous
//
#include <hip/hip_runtime.h>

static constexpr int H = 2048;
static constexpr int W = 2048;
static constexpr int BLOCK = 256;
// 2 cols x 2 rows of pixels per thread; block tile = 512 cols x 2 rows
static constexpr int NBLOCKS = (H / 2) * (W / (BLOCK * 2));   // 1024*4 = 4096
static constexpr int RBLOCK = 1024;

__device__ __forceinline__ float fexp2(float x){ return __builtin_amdgcn_exp2f(x); }
__device__ __forceinline__ float flog2(float x){ return __builtin_amdgcn_logf(x); }
__device__ __forceinline__ float frcp (float x){ return __builtin_amdgcn_rcpf(x); }

static constexpr float S_   = 0.84932180028801905f;   // sqrt(0.5*log2(e))
static constexpr float LN2_ = 0.69314718055994531f;

// One pixel's 9-tap term. 5 precomputed (e, e*t) pairs per image (2 horizontal,
// 3 shared vertical/diagonal) + 3 inline neighbor taps (the unshared row).
//   t=(d*S)^2, e=exp2(-t)=exp(-d^2/2); G=1+sum e; S=sum e*t
//   pacc = Sp*ip + Sq*iq + log2(Gp*Gq) + 2*sum m*log2 m ; out = -ln2*sum(pacc)
__device__ __forceinline__ float pixel_term(
    float an0, float an1, float an2, float ca,
    float hAe0, float hAt0, float hAe1, float hAt1,
    float vAe0, float vAt0, float vAe1, float vAt1, float vAe2, float vAt2,
    float bn0, float bn1, float bn2, float cb,
    float hBe0, float hBt0, float hBe1, float hBt1,
    float vBe0, float vBt0, float vBe1, float vBt1, float vBe2, float vBt2)
{
    float d, t;
    d = an0 - ca; d *= S_; t = d*d; const float iAe0 = fexp2(-t); const float iAt0 = iAe0*t;
    d = an1 - ca; d *= S_; t = d*d; const float iAe1 = fexp2(-t); const float iAt1 = iAe1*t;
    d = an2 - ca; d *= S_; t = d*d; const float iAe2 = fexp2(-t); const float iAt2 = iAe2*t;
    d = bn0 - cb; d *= S_; t = d*d; const float iBe0 = fexp2(-t); const float iBt0 = iBe0*t;
    d = bn1 - cb; d *= S_; t = d*d; const float iBe1 = fexp2(-t); const float iBt1 = iBe1*t;
    d = bn2 - cb; d *= S_; t = d*d; const float iBe2 = fexp2(-t); const float iBt2 = iBe2*t;

    const float Gp = 1.f + hAe0 + hAe1 + vAe0 + vAe1 + vAe2 + iAe0 + iAe1 + iAe2;
    const float Sp =       hAt0 + hAt1 + vAt0 + vAt1 + vAt2 + iAt0 + iAt1 + iAt2;
    const float Gq = 1.f + hBe0 + hBe1 + vBe0 + vBe1 + vBe2 + iBe0 + iBe1 + iBe2;
    const float Sq =       hBt0 + hBt1 + vBt0 + vBt1 + vBt2 + iBt0 + iBt1 + iBt2;

    // one rcp instead of two: ip = 1/Gp = rcp(Gp*Gq)*Gq, iq likewise
    const float P  = Gp * Gq;
    const float rP = frcp(P);
    const float ip = rP * Gq;
    const float iq = rP * Gp;
    const float hp = 0.5f * ip, hq = 0.5f * iq;

    float m = hp + hq;                       // center tap (g=1 for both)
    float mll = m * flog2(m);
#define MT(ea, eb) m = fmaf((ea), hp, (eb)*hq); mll = fmaf(m, flog2(m), mll);
    MT(hAe0, hBe0) MT(hAe1, hBe1)
    MT(vAe0, vBe0) MT(vAe1, vBe1) MT(vAe2, vBe2)
    MT(iAe0, iBe0) MT(iAe1, iBe1) MT(iAe2, iBe2)
#undef MT

    return fmaf(Sp, ip, Sq*iq) + flog2(P) + 2.f*mll;
}

__global__ __launch_bounds__(BLOCK, 4) void jsd_pixel_kernel(
    const float* __restrict__ A, const float* __restrict__ B,
    float* __restrict__ partial)
{
    const int bid   = blockIdx.x;
    const int ytile = bid >> 2;                      // 1024 row-pairs
    const int y0    = ytile << 1;                    // top pixel row (R1)
    const int x0    = ((bid & 3) << 9) + (threadIdx.x << 1);
    const int base  = y0 * W + x0;
    const bool hasL = (x0 > 0);
    const bool hasR = (x0 + 2 < W);

    // Rows: R0=y0-1 (mask), R1=y0, R2=y0+1, R3=y0+2 (mask). Cols C0..C3 = x0-1..x0+2.
    float a00,a01,a02,a03, a10,a11,a12,a13, a20,a21,a22,a23, a30,a31,a32,a33;
    float b00,b01,b02,b03, b10,b11,b12,b13, b20,b21,b22,b23, b30,b31,b32,b33;

#define LOAD_ROW(p0,p1,p2,p3, ptr, off) \
    { const float2 q_ = *(const float2*)((ptr)+(off)); p1=q_.x; p2=q_.y; \
      p0 = hasL ? (ptr)[(off)-1] : 0.f; p3 = hasR ? (ptr)[(off)+2] : 0.f; }

    LOAD_ROW(a10,a11,a12,a13, A, base)
    LOAD_ROW(a20,a21,a22,a23, A, base + W)
    LOAD_ROW(b10,b11,b12,b13, B, base)
    LOAD_ROW(b20,b21,b22,b23, B, base + W)
    if (y0 > 0) {                                     // block-uniform
        LOAD_ROW(a00,a01,a02,a03, A, base - W)
        LOAD_ROW(b00,b01,b02,b03, B, base - W)
    } else { a00=a01=a02=a03=0.f; b00=b01=b02=b03=0.f; }
    if (y0 + 2 < H) {
        LOAD_ROW(a30,a31,a32,a33, A, base + 2*W)
        LOAD_ROW(b30,b31,b32,b33, B, base + 2*W)
    } else { a30=a31=a32=a33=0.f; b30=b31=b32=b33=0.f; }
#undef LOAD_ROW

    // Precomputed pair exps: e = exp2(-t), w/t = e*t.
#define PAIR(e,t, u,v) float e,t; { float d_=(v)-(u); d_*=S_; const float q_=d_*d_; \
                                    e=fexp2(-q_); t=e*q_; }
    // horizontal pairs within rows R1, R2 (shared by adjacent pixels)
    PAIR(hA10,tA10, a10,a11) PAIR(hA11,tA11, a11,a12) PAIR(hA12,tA12, a12,a13)
    PAIR(hA20,tA20, a20,a21) PAIR(hA21,tA21, a21,a22) PAIR(hA22,tA22, a22,a23)
    PAIR(hB10,tB10, b10,b11) PAIR(hB11,tB11, b11,b12) PAIR(hB12,tB12, b12,b13)
    PAIR(hB20,tB20, b20,b21) PAIR(hB21,tB21, b21,b22) PAIR(hB22,tB22, b22,b23)
    // vertical/diagonal edges R1<->R2: vXY = edge (R1 col X, R2 col Y)
    PAIR(vA10,wA10, a11,a20) PAIR(vA11,wA11, a11,a21) PAIR(vA12,wA12, a11,a22)
    PAIR(vA21,wA21, a12,a21) PAIR(vA22,wA22, a12,a22) PAIR(vA23,wA23, a12,a23)
    PAIR(vA01,wA01, a10,a21) PAIR(vA32,wA32, a13,a22)
    PAIR(vB10,wB10, b11,b20) PAIR(vB11,wB11, b11,b21) PAIR(vB12,wB12, b11,b22)
    PAIR(vB21,wB21, b12,b21) PAIR(vB22,wB22, b12,b22) PAIR(vB23,wB23, b12,b23)
    PAIR(vB01,wB01, b10,b21) PAIR(vB32,wB32, b13,b22)
#undef PAIR

    float pacc;
    // (R1,C1): up = R0 cols 0..2; down edges v10,v11,v12
    pacc  = pixel_term(a00,a01,a02, a11, hA10,tA10, hA11,tA11,
                       vA10,wA10, vA11,wA11, vA12,wA12,
                       b00,b01,b02, b11, hB10,tB10, hB11,tB11,
                       vB10,wB10, vB11,wB11, vB12,wB12);
    // (R1,C2): up = R0 cols 1..3; down edges v21,v22,v23
    pacc += pixel_term(a01,a02,a03, a12, hA11,tA11, hA12,tA12,
                       vA21,wA21, vA22,wA22, vA23,wA23,
                       b01,b02,b03, b12, hB11,tB11, hB12,tB12,
                       vB21,wB21, vB22,wB22, vB23,wB23);
    // (R2,C1): down = R3 cols 0..2; up edges v01,v11,v21
    pacc += pixel_term(a30,a31,a32, a21, hA20,tA20, hA21,tA21,
                       vA01,wA01, vA11,wA11, vA21,wA21,
                       b30,b31,b32, b21, hB20,tB20, hB21,tB21,
                       vB01,wB01, vB11,wB11, vB21,wB21);
    // (R2,C2): down = R3 cols 1..3; up edges v12,v22,v32
    pacc += pixel_term(a31,a32,a33, a22, hA21,tA21, hA22,tA22,
                       vA12,wA12, vA22,wA22, vA32,wA32,
                       b31,b32,b33, b22, hB21,tB21, hB22,tB22,
                       vB12,wB12, vB22,wB22, vB32,wB32);

    // wave64 reduce, cross-wave via LDS
    #pragma unroll
    for (int off = 32; off > 0; off >>= 1)
        pacc += __shfl_down(pacc, off, 64);

    __shared__ float wsum[BLOCK / 64];
    const int lane = threadIdx.x & 63;
    const int wid  = threadIdx.x >> 6;
    if (lane == 0) wsum[wid] = pacc;
    __syncthreads();
    if (threadIdx.x == 0)
        partial[blockIdx.x] = wsum[0] + wsum[1] + wsum[2] + wsum[3];
}

// Deterministic final reduce of NBLOCKS partials (single block, 16 waves).
__global__ __launch_bounds__(RBLOCK) void jsd_final_reduce(
    const float* __restrict__ partial, float* __restrict__ out)
{
    float s = 0.f;
    #pragma unroll
    for (int i = 0; i < NBLOCKS / RBLOCK; ++i)
        s += partial[i * RBLOCK + threadIdx.x];

    #pragma unroll
    for (int off = 32; off > 0; off >>= 1)
        s += __shfl_down(s, off, 64);

    __shared__ float wsum[RBLOCK / 64];
    const int lane = threadIdx.x & 63;
    const int wid  = threadIdx.x >> 6;
    if (lane == 0) wsum[wid] = s;
    __syncthreads();
    if (threadIdx.x == 0) {
        float t = 0.f;
        #pragma unroll
        for (int i = 0; i < RBLOCK / 64; ++i) t += wsum[i];
        out[0] = -LN2_ * t;
    }
}

extern "C" void kernel_launch(void* const* d_in, const int* in_sizes, int n_in,
                              void* d_out, int out_size, void* d_ws, size_t ws_size,
                              hipStream_t stream) {
    const float* A = (const float*)d_in[0];
    const float* B = (const float*)d_in[1];
    float* out = (float*)d_out;
    float* partial = (float*)d_ws;    // NBLOCKS floats = 16 KiB

    jsd_pixel_kernel<<<NBLOCKS, BLOCK, 0, stream>>>(A, B, partial);
    jsd_final_reduce<<<1, RBLOCK, 0, stream>>>(partial, out);
}